// Round 12
// baseline (59.407 us; speedup 1.0000x reference)
//
#include <hip/hip_runtime.h>
#include <stdint.h>

#define NBITS  8
#define SLICE  1024
#define OUTF   512
#define INF    8192
#define TOPK   32
#define BATCHN 4096

#define ROWS    INF                        // 8192 table rows, 64 words each
#define DUMMY_B (ROWS * 64 * 4)            // BYTE offset of dummy row (fields=1)
#define TBL2_B  ((ROWS + 1) * 64 * 4)      // BYTE offset of complement table

// monotone float->sortable-key bijection (general path only)
__device__ __forceinline__ uint32_t fkey_u(uint32_t u) {
  uint32_t m = ((uint32_t)((int32_t)u >> 31)) | 0x80000000u;
  return u ^ m;
}

// ---- DPP cross-lane helpers (wave64, rocPRIM-standard gfx9 patterns) -------
template <int CTRL, int RMASK>
__device__ __forceinline__ int dpp_zf(int x) {    // zero-fill (for sums)
  return __builtin_amdgcn_update_dpp(0, x, CTRL, RMASK, 0xF, true);
}
template <int CTRL, int RMASK>
__device__ __forceinline__ uint32_t dpp_id(uint32_t x) {  // identity-fill
  return (uint32_t)__builtin_amdgcn_update_dpp((int)x, (int)x, CTRL, RMASK, 0xF, false);
}
// inclusive prefix sum across the full wave
__device__ __forceinline__ int wave_prefix_incl(int v) {
  v += dpp_zf<0x111, 0xF>(v);   // row_shr:1
  v += dpp_zf<0x112, 0xF>(v);   // row_shr:2
  v += dpp_zf<0x114, 0xF>(v);   // row_shr:4
  v += dpp_zf<0x118, 0xF>(v);   // row_shr:8
  v += dpp_zf<0x142, 0xA>(v);   // row_bcast:15 -> rows 1,3
  v += dpp_zf<0x143, 0xC>(v);   // row_bcast:31 -> rows 2,3
  return v;
}
__device__ __forceinline__ uint32_t wave_max_u32(uint32_t v) {
  uint32_t t;
  t = dpp_id<0x111, 0xF>(v); v = v > t ? v : t;
  t = dpp_id<0x112, 0xF>(v); v = v > t ? v : t;
  t = dpp_id<0x114, 0xF>(v); v = v > t ? v : t;
  t = dpp_id<0x118, 0xF>(v); v = v > t ? v : t;
  t = dpp_id<0x142, 0xA>(v); v = v > t ? v : t;
  t = dpp_id<0x143, 0xC>(v); v = v > t ? v : t;
  return (uint32_t)__builtin_amdgcn_readlane((int)v, 63);
}
__device__ __forceinline__ uint32_t wave_min_u32(uint32_t v) {
  uint32_t t;
  t = dpp_id<0x111, 0xF>(v); v = v < t ? v : t;
  t = dpp_id<0x112, 0xF>(v); v = v < t ? v : t;
  t = dpp_id<0x114, 0xF>(v); v = v < t ? v : t;
  t = dpp_id<0x118, 0xF>(v); v = v < t ? v : t;
  t = dpp_id<0x142, 0xA>(v); v = v < t ? v : t;
  t = dpp_id<0x143, 0xC>(v); v = v < t ? v : t;
  return (uint32_t)__builtin_amdgcn_readlane((int)v, 63);
}
// float wave min/max of per-lane values (bit-moves via DPP, fmin/fmax combine)
__device__ __forceinline__ float wave_maxf(float v) {
  float t;
  t = __uint_as_float(dpp_id<0x111,0xF>(__float_as_uint(v))); v = fmaxf(v,t);
  t = __uint_as_float(dpp_id<0x112,0xF>(__float_as_uint(v))); v = fmaxf(v,t);
  t = __uint_as_float(dpp_id<0x114,0xF>(__float_as_uint(v))); v = fmaxf(v,t);
  t = __uint_as_float(dpp_id<0x118,0xF>(__float_as_uint(v))); v = fmaxf(v,t);
  t = __uint_as_float(dpp_id<0x142,0xA>(__float_as_uint(v))); v = fmaxf(v,t);
  t = __uint_as_float(dpp_id<0x143,0xC>(__float_as_uint(v))); v = fmaxf(v,t);
  return __uint_as_float((uint32_t)__builtin_amdgcn_readlane((int)__float_as_uint(v), 63));
}
__device__ __forceinline__ float wave_minf(float v) {
  float t;
  t = __uint_as_float(dpp_id<0x111,0xF>(__float_as_uint(v))); v = fminf(v,t);
  t = __uint_as_float(dpp_id<0x112,0xF>(__float_as_uint(v))); v = fminf(v,t);
  t = __uint_as_float(dpp_id<0x114,0xF>(__float_as_uint(v))); v = fminf(v,t);
  t = __uint_as_float(dpp_id<0x118,0xF>(__float_as_uint(v))); v = fminf(v,t);
  t = __uint_as_float(dpp_id<0x142,0xA>(__float_as_uint(v))); v = fminf(v,t);
  t = __uint_as_float(dpp_id<0x143,0xC>(__float_as_uint(v))); v = fminf(v,t);
  return __uint_as_float((uint32_t)__builtin_amdgcn_readlane((int)__float_as_uint(v), 63));
}

// ---------------------------------------------------------------------------
// prep: pack b = (W>=0)+(Wm>=0) in {0,1,2} as 4-bit fields, 8 cols per u32.
// Word w of row r holds columns {w + 64*i}, field i.  Also writes the
// complement table (2-b) and a dummy row of 1-fields (zero contribution).
// ---------------------------------------------------------------------------
__global__ __launch_bounds__(256) void prep_kernel(
    const float* __restrict__ W, const float* __restrict__ Wm,
    uint32_t* __restrict__ tbl)
{
  int tid = blockIdx.x * blockDim.x + threadIdx.x;   // 8192*64 threads
  int r = tid >> 6;        // row 0..8191  (= n*1024 + s)
  int w = tid & 63;        // word 0..63
  const float* wr = W  + (size_t)r * OUTF;
  const float* mr = Wm + (size_t)r * OUTF;
  uint32_t word = 0;
#pragma unroll
  for (int i = 0; i < 8; ++i) {
    int col = w + 64 * i;
    uint32_t b = (wr[col] >= 0.0f ? 1u : 0u) + (mr[col] >= 0.0f ? 1u : 0u);
    word |= b << (4 * i);
  }
  tbl[tid] = word;
  tbl[(TBL2_B / 4) + tid] = 0x22222222u - word;   // fields 2-b (b<=2, no borrow)
  if (tid < 64) tbl[(DUMMY_B / 4) + tid] = 0x11111111u;
}

// ---------------------------------------------------------------------------
// main: one block per batch row, 8 waves; wave n handles bit-slice n.
//  FAST PIPELINE (lo_f >= FLT_MIN, i.e. every lane's max is a positive normal
//  float -- ubiquitous): NO key map.  Raw positive-float bit patterns are in
//  sort order, so the histogram bins raw bits ((lo,hi] underflow guard
//  provably excludes zeros/negatives/subnormals), and all count/selection
//  compares are exact float compares on the loaded values.  Every taken
//  element is strictly positive => positive table, partial = 32 constant,
//  even in the tie path.
//  GENERAL PIPELINE (rare): r11's key-mapped search, bit-identical.
// ---------------------------------------------------------------------------
__global__ __launch_bounds__(512, 4) void main_kernel(
    const float* __restrict__ latent,
    const uint32_t* __restrict__ tbl,
    float* __restrict__ out, int* __restrict__ partial)
{
  __shared__ __align__(16) uint32_t sel[NBITS][TOPK];   // BYTE offsets into tbl
  __shared__ float sums[NBITS][OUTF];
  __shared__ int   hist[NBITS][64];

  const int b    = blockIdx.x;
  const int wv   = threadIdx.x >> 6;        // bit index n
  const int lane = threadIdx.x & 63;

  // defensive prefill: every sel slot is a valid (zero-contribution) row
  if (lane < TOPK) sel[wv][lane] = (uint32_t)DUMMY_B;

  // ---- load 16 contiguous values, track lane float max --------------------
  const float4* src =
      (const float4*)(latent + (size_t)b * INF + (size_t)wv * SLICE + lane * 16);
  float v[16];
  float lmaxf = -__builtin_huge_valf();
#pragma unroll
  for (int q = 0; q < 4; ++q) {
    float4 f = src[q];
    v[4*q+0] = f.x; v[4*q+1] = f.y; v[4*q+2] = f.z; v[4*q+3] = f.w;
    lmaxf = fmaxf(fmaxf(fmaxf(lmaxf, f.x), fmaxf(f.y, f.z)), f.w);
  }

  // ---- seeded bounds (valid for ANY input) --------------------------------
  // lo_f = wave-min of lane maxima (>=64 elems >= lo_f => T >= lo_f)
  // hi_f = wave-max of lane maxima (= global max)
  const float lo_f = wave_minf(lmaxf);
  const float hi_f = wave_maxf(lmaxf);

  const uint32_t pbase = ((uint32_t)(wv * SLICE + lane * 16)) << 8;  // row*256

  if (lo_f >= 1.17549435e-38f) {
    // =================== FAST PIPELINE (positive-normal bracket) ===========
    uint32_t lo = __float_as_uint(lo_f);
    uint32_t hi = __float_as_uint(hi_f);

    uint32_t midE = 0;  float TF = 0.0f;  uint32_t cE = 0;
    int base  = 0;
    int state = 0;                          // 0 searching, 1 fast, 2 ties(TF)

#pragma unroll 1
    for (int round = 0; round < 2; ++round) {
      if (lo >= hi) break;
      uint32_t width = hi - lo;             // >= 1
      int bl  = 32 - __builtin_clz(width);
      int shr = bl > 6 ? bl - 6 : 0;        // (width-1)>>shr <= 63
      hist[wv][lane] = 0;
#pragma unroll
      for (int j = 0; j < 16; ++j) {
        uint32_t d1 = __float_as_uint(v[j]) - lo - 1u;  // underflow => huge
        if (d1 < width)                     // bins ONLY (lo, hi]
          atomicAdd(&hist[wv][d1 >> shr], 1);
      }
      int myc = hist[wv][lane];
      int P   = wave_prefix_incl(myc);
      int tot = __builtin_amdgcn_readlane(P, 63);
      int suf = base + (tot - P + myc);     // count(key >= lo+1+(lane<<shr))
      unsigned long long m32 = __ballot(suf == TOPK);
      if (m32) {                            // exact top-k at a bin edge
        int l = (int)__builtin_ctzll(m32);
        midE = lo + 1u + ((uint32_t)l << shr);
        float mf = __uint_as_float(midE);
        uint32_t c = 0;
#pragma unroll
        for (int j = 0; j < 16; ++j) c += (v[j] >= mf) ? 1u : 0u;
        cE = c; state = 1; break;
      }
      unsigned long long mge = __ballot(suf > TOPK);
      if (mge == 0ULL) { TF = __uint_as_float(lo); state = 2; break; }
      int bstar = 63 - (int)__builtin_clzll(mge);
      uint32_t nlo = lo + 1u + ((uint32_t)bstar << shr);
      if (bstar < 63) {
        base = __builtin_amdgcn_readlane(suf, bstar + 1);  // count(> new hi)
        hi   = lo + ((uint32_t)(bstar + 1) << shr);
      }
      lo = nlo;
    }

    if (state == 0) {                       // residual exact bisection
      while (lo < hi) {
        uint32_t d   = hi - lo;
        uint32_t mid = lo + (d >> 1) + (d & 1u);
        float mf = __uint_as_float(mid);
        uint32_t c = 0;
#pragma unroll
        for (int j = 0; j < 16; ++j) c += (v[j] >= mf) ? 1u : 0u;
        int cnt = __builtin_amdgcn_readlane(wave_prefix_incl((int)c), 63);
        if (cnt == TOPK) { midE = mid; cE = c; state = 1; break; }
        if (cnt > TOPK) lo = mid; else hi = mid - 1u;
      }
      if (state == 0) { TF = __uint_as_float(lo); state = 2; }
    }

    if (state == 1) {
      // ---- tie-free: take set is exactly {v >= midE_f}, all positive ------
      const float mf = __uint_as_float(midE);
      int slot = wave_prefix_incl((int)cE) - (int)cE;   // exclusive prefix
#pragma unroll
      for (int j = 0; j < 16; ++j) {
        if (v[j] >= mf) sel[wv][slot++] = pbase + (j << 8);
      }
    } else {
      // ---- ties at TF (>0): stable lowest-index-first, all positive -------
      int cgt = 0, ceq = 0;
#pragma unroll
      for (int j = 0; j < 16; ++j) { cgt += (v[j] > TF); ceq += (v[j] == TF); }
      int packed  = (cgt << 16) | ceq;
      int sc_incl = wave_prefix_incl(packed);
      int tot2    = __builtin_amdgcn_readlane(sc_incl, 63);
      int total_g = tot2 >> 16;
      int nties   = TOPK - total_g;
      int excl    = sc_incl - packed;
      int posg    = excl >> 16;
      int pose    = excl & 0xFFFF;
#pragma unroll
      for (int j = 0; j < 16; ++j) {
        bool isgt   = v[j] > TF;
        bool iseq   = (v[j] == TF);
        bool takeeq = iseq && (pose < nties);
        int slot = isgt ? posg : (total_g + pose);
        if (isgt || takeeq) sel[wv][slot] = pbase + (j << 8);
        posg += isgt ? 1 : 0;
        pose += iseq ? 1 : 0;
      }
    }
    if (lane == 0) partial[wv * BATCHN + b] = TOPK;   // all taken > 0
  } else {
    // =================== GENERAL PIPELINE (r11, key-mapped, exact) =========
    uint32_t key[16];
    uint32_t lmax = 0u;
#pragma unroll
    for (int j = 0; j < 16; ++j) {
      uint32_t k = fkey_u(__float_as_uint(v[j]));
      key[j] = k;
      lmax = lmax > k ? lmax : k;
    }
    uint32_t lo = wave_min_u32(lmax);
    uint32_t hi = wave_max_u32(lmax);

    uint32_t T = 0, midE = 0, cE = 0;
    int base  = 0;
    int state = 0;

#pragma unroll 1
    for (int round = 0; round < 2; ++round) {
      if (lo >= hi) break;
      uint32_t width = hi - lo;
      int bl  = 32 - __builtin_clz(width);
      int shr = bl > 6 ? bl - 6 : 0;
      hist[wv][lane] = 0;
#pragma unroll
      for (int j = 0; j < 16; ++j) {
        uint32_t d1 = key[j] - lo - 1u;
        if (d1 < width)
          atomicAdd(&hist[wv][d1 >> shr], 1);
      }
      int myc = hist[wv][lane];
      int P   = wave_prefix_incl(myc);
      int tot = __builtin_amdgcn_readlane(P, 63);
      int suf = base + (tot - P + myc);
      unsigned long long m32 = __ballot(suf == TOPK);
      if (m32) {
        int l = (int)__builtin_ctzll(m32);
        midE = lo + 1u + ((uint32_t)l << shr);
        uint32_t c = 0;
#pragma unroll
        for (int j = 0; j < 16; ++j) c += (key[j] >= midE) ? 1u : 0u;
        cE = c; state = 1; break;
      }
      unsigned long long mge = __ballot(suf > TOPK);
      if (mge == 0ULL) { T = lo; state = 2; break; }
      int bstar = 63 - (int)__builtin_clzll(mge);
      uint32_t nlo = lo + 1u + ((uint32_t)bstar << shr);
      if (bstar < 63) {
        base = __builtin_amdgcn_readlane(suf, bstar + 1);
        hi   = lo + ((uint32_t)(bstar + 1) << shr);
      }
      lo = nlo;
    }

    if (state == 0) {
      while (lo < hi) {
        uint32_t d   = hi - lo;
        uint32_t mid = lo + (d >> 1) + (d & 1u);
        uint32_t c = 0;
#pragma unroll
        for (int j = 0; j < 16; ++j) c += (key[j] >= mid) ? 1u : 0u;
        int cnt = __builtin_amdgcn_readlane(wave_prefix_incl((int)c), 63);
        if (cnt == TOPK) { midE = mid; cE = c; state = 1; break; }
        if (cnt > TOPK) lo = mid; else hi = mid - 1u;
      }
      if (state == 0) { T = lo; state = 2; }
    }

    int nzl = 0;
    if (state == 1) {
      int slot = wave_prefix_incl((int)cE) - (int)cE;
#pragma unroll
      for (int j = 0; j < 16; ++j) {
        uint32_t kk = key[j];
        if (kk >= midE) {
          bool ispos = kk > 0x80000000u;
          bool isneg = kk < 0x7FFFFFFFu;
          uint32_t off = ispos ? (pbase + (j << 8))
                       : (isneg ? (pbase + (j << 8) + TBL2_B) : (uint32_t)DUMMY_B);
          sel[wv][slot++] = off;
          nzl += (ispos || isneg) ? 1 : 0;
        }
      }
    } else {
      int cgt = 0, ceq = 0;
#pragma unroll
      for (int j = 0; j < 16; ++j) { cgt += (key[j] > T); ceq += (key[j] == T); }
      int packed  = (cgt << 16) | ceq;
      int sc_incl = wave_prefix_incl(packed);
      int tot2    = __builtin_amdgcn_readlane(sc_incl, 63);
      int total_g = tot2 >> 16;
      int nties   = TOPK - total_g;
      int excl    = sc_incl - packed;
      int posg    = excl >> 16;
      int pose    = excl & 0xFFFF;
#pragma unroll
      for (int j = 0; j < 16; ++j) {
        uint32_t kk  = key[j];
        bool isgt    = kk > T;
        bool iseq    = (kk == T);
        bool takeeq  = iseq && (pose < nties);
        bool take    = isgt || takeeq;
        bool ispos   = kk > 0x80000000u;
        bool isneg   = kk < 0x7FFFFFFFu;
        uint32_t off = ispos ? (pbase + (j << 8))
                     : (isneg ? (pbase + (j << 8) + TBL2_B) : (uint32_t)DUMMY_B);
        int slot = isgt ? posg : (total_g + pose);
        if (take) sel[wv][slot] = off;
        posg += isgt ? 1 : 0;
        pose += iseq ? 1 : 0;
        nzl  += (take && (ispos || isneg)) ? 1 : 0;
      }
    }
    int cnzP = wave_prefix_incl(nzl);
    if (lane == 63) partial[wv * BATCHN + b] = cnzP;
  }

  // ---- gather: 32 loads, wave-uniform offsets -> SGPR addressing ----------
  uint32_t offr[TOPK];
  {
    const uint4* sp = (const uint4*)sel[wv];
#pragma unroll
    for (int q = 0; q < TOPK / 4; ++q) {
      uint4 e4 = sp[q];
      offr[4*q+0] = e4.x; offr[4*q+1] = e4.y;
      offr[4*q+2] = e4.z; offr[4*q+3] = e4.w;
    }
  }
  const uint32_t lb = (uint32_t)lane << 2;
  const char* tbase = (const char*)tbl;

#define LD(i)                                                                  \
  uint32_t w##i;                                                               \
  {                                                                            \
    uint32_t ro = (uint32_t)__builtin_amdgcn_readfirstlane((int)offr[i]);      \
    w##i = *(const uint32_t*)(tbase + (size_t)ro + lb);                        \
  }
  LD(0)  LD(1)  LD(2)  LD(3)  LD(4)  LD(5)  LD(6)  LD(7)
  LD(8)  LD(9)  LD(10) LD(11) LD(12) LD(13) LD(14) LD(15)
  LD(16) LD(17) LD(18) LD(19) LD(20) LD(21) LD(22) LD(23)
  LD(24) LD(25) LD(26) LD(27) LD(28) LD(29) LD(30) LD(31)
#undef LD
  asm volatile("" ::
    "v"(w0),"v"(w1),"v"(w2),"v"(w3),"v"(w4),"v"(w5),"v"(w6),"v"(w7),
    "v"(w8),"v"(w9),"v"(w10),"v"(w11),"v"(w12),"v"(w13),"v"(w14),"v"(w15));
  asm volatile("" ::
    "v"(w16),"v"(w17),"v"(w18),"v"(w19),"v"(w20),"v"(w21),"v"(w22),"v"(w23),
    "v"(w24),"v"(w25),"v"(w26),"v"(w27),"v"(w28),"v"(w29),"v"(w30),"v"(w31));

  // 5 independent <=7-deep chunks (4-bit fields: <=7*2=14 per nibble, safe)
  uint32_t g0 = (((w0 + w1) + (w2 + w3)) + ((w4 + w5) + w6));
  uint32_t g1 = (((w7 + w8) + (w9 + w10)) + ((w11 + w12) + w13));
  uint32_t g2 = (((w14 + w15) + (w16 + w17)) + ((w18 + w19) + w20));
  uint32_t g3 = (((w21 + w22) + (w23 + w24)) + ((w25 + w26) + w27));
  uint32_t g4 = ((w28 + w29) + (w30 + w31));
  const uint32_t M = 0x0F0F0F0Fu;
  uint32_t acc0 = (g0 & M) + (g1 & M) + (g2 & M) + (g3 & M) + (g4 & M);
  uint32_t acc1 = ((g0 >> 4) & M) + ((g1 >> 4) & M) + ((g2 >> 4) & M)
                + ((g3 >> 4) & M) + ((g4 >> 4) & M);

  // ---- per-column S = scale*(2*F - 64) via cvt+fma -------------------------
  const float scale_n = 1.0f / (float)(1 << wv);   // 2^(6-n)*4/256 = 2^-n
  const float sA = 2.0f * scale_n;
  const float sB = -64.0f * scale_n;
#pragma unroll
  for (int i2 = 0; i2 < 4; ++i2) {
    float f0 = (float)(int)((acc0 >> (8 * i2)) & 0xFFu);
    float f1 = (float)(int)((acc1 >> (8 * i2)) & 0xFFu);
    sums[wv][lane + 128 * i2]      = fmaf(f0, sA, sB);
    sums[wv][lane + 128 * i2 + 64] = fmaf(f1, sA, sB);
  }

  __syncthreads();

  // ---- cumsum over bits, store result[n][b][col] --------------------------
  const int col = threadIdx.x;               // 0..511
  float racc = 0.0f;
  float* obase = out + 8 + (size_t)b * OUTF + col;
#pragma unroll
  for (int n2 = 0; n2 < NBITS; ++n2) {
    racc += sums[n2][col];
    obase[(size_t)n2 * BATCHN * OUTF] = racc;
  }
}

// ---------------------------------------------------------------------------
// finalize: latent_group[n] = (sum_b partial[n][b]) / BATCH
// ---------------------------------------------------------------------------
__global__ __launch_bounds__(512) void fin_kernel(
    const int* __restrict__ partial, float* __restrict__ out)
{
  const int wv   = threadIdx.x >> 6;
  const int lane = threadIdx.x & 63;
  const int* p = partial + wv * BATCHN;
  int s = 0;
#pragma unroll
  for (int k = 0; k < BATCHN / 64; ++k)
    s += p[lane + 64 * k];
#pragma unroll
  for (int d = 32; d >= 1; d >>= 1)
    s += __shfl_down(s, d);
  if (lane == 0) out[wv] = (float)s * (1.0f / (float)BATCHN);
}

extern "C" void kernel_launch(void* const* d_in, const int* in_sizes, int n_in,
                              void* d_out, int out_size, void* d_ws, size_t ws_size,
                              hipStream_t stream)
{
  const float* latent = (const float*)d_in[0];
  const float* W      = (const float*)d_in[1];
  const float* Wm     = (const float*)d_in[2];
  float* out = (float*)d_out;

  int*      partial = (int*)d_ws;                          // 128 KB
  uint32_t* tbl     = (uint32_t*)((char*)d_ws + 131072);   // ~4.2 MB tables

  prep_kernel<<<(INF * 64) / 256, 256, 0, stream>>>(W, Wm, tbl);
  main_kernel<<<BATCHN, 512, 0, stream>>>(latent, tbl, out, partial);
  fin_kernel<<<1, 512, 0, stream>>>(partial, out);
}

// Round 13
// 59.002 us; speedup vs baseline: 1.0069x; 1.0069x over previous
//
#include <hip/hip_runtime.h>
#include <stdint.h>

#define NBITS  8
#define SLICE  1024
#define OUTF   512
#define INF    8192
#define TOPK   32
#define BATCHN 4096

#define ROWS    INF                        // 8192 table rows, 64 words each
#define DUMMY_B (ROWS * 64 * 4)            // BYTE offset of dummy row (fields=1)
#define TBL2_B  ((ROWS + 1) * 64 * 4)      // BYTE offset of complement table

// monotone float->sortable-key bijection
__device__ __forceinline__ uint32_t fkey_u(uint32_t u) {
  uint32_t m = ((uint32_t)((int32_t)u >> 31)) | 0x80000000u;
  return u ^ m;
}

// ---- DPP cross-lane helpers (wave64, rocPRIM-standard gfx9 patterns) -------
template <int CTRL, int RMASK>
__device__ __forceinline__ int dpp_zf(int x) {    // zero-fill (for sums)
  return __builtin_amdgcn_update_dpp(0, x, CTRL, RMASK, 0xF, true);
}
template <int CTRL, int RMASK>
__device__ __forceinline__ uint32_t dpp_id(uint32_t x) {  // identity-fill
  return (uint32_t)__builtin_amdgcn_update_dpp((int)x, (int)x, CTRL, RMASK, 0xF, false);
}
// inclusive prefix sum across the full wave
__device__ __forceinline__ int wave_prefix_incl(int v) {
  v += dpp_zf<0x111, 0xF>(v);   // row_shr:1
  v += dpp_zf<0x112, 0xF>(v);   // row_shr:2
  v += dpp_zf<0x114, 0xF>(v);   // row_shr:4
  v += dpp_zf<0x118, 0xF>(v);   // row_shr:8
  v += dpp_zf<0x142, 0xA>(v);   // row_bcast:15 -> rows 1,3
  v += dpp_zf<0x143, 0xC>(v);   // row_bcast:31 -> rows 2,3
  return v;
}
__device__ __forceinline__ uint32_t wave_max_u32(uint32_t v) {
  uint32_t t;
  t = dpp_id<0x111, 0xF>(v); v = v > t ? v : t;
  t = dpp_id<0x112, 0xF>(v); v = v > t ? v : t;
  t = dpp_id<0x114, 0xF>(v); v = v > t ? v : t;
  t = dpp_id<0x118, 0xF>(v); v = v > t ? v : t;
  t = dpp_id<0x142, 0xA>(v); v = v > t ? v : t;
  t = dpp_id<0x143, 0xC>(v); v = v > t ? v : t;
  return (uint32_t)__builtin_amdgcn_readlane((int)v, 63);
}
__device__ __forceinline__ uint32_t wave_min_u32(uint32_t v) {
  uint32_t t;
  t = dpp_id<0x111, 0xF>(v); v = v < t ? v : t;
  t = dpp_id<0x112, 0xF>(v); v = v < t ? v : t;
  t = dpp_id<0x114, 0xF>(v); v = v < t ? v : t;
  t = dpp_id<0x118, 0xF>(v); v = v < t ? v : t;
  t = dpp_id<0x142, 0xA>(v); v = v < t ? v : t;
  t = dpp_id<0x143, 0xC>(v); v = v < t ? v : t;
  return (uint32_t)__builtin_amdgcn_readlane((int)v, 63);
}

// ---------------------------------------------------------------------------
// prep: pack b = (W>=0)+(Wm>=0) in {0,1,2} as 4-bit fields, 8 cols per u32.
// Word w of row r holds columns {w + 64*i}, field i.  Also writes the
// complement table (2-b) and a dummy row of 1-fields (zero contribution).
// ---------------------------------------------------------------------------
__global__ __launch_bounds__(256) void prep_kernel(
    const float* __restrict__ W, const float* __restrict__ Wm,
    uint32_t* __restrict__ tbl)
{
  int tid = blockIdx.x * blockDim.x + threadIdx.x;   // 8192*64 threads
  int r = tid >> 6;        // row 0..8191  (= n*1024 + s)
  int w = tid & 63;        // word 0..63
  const float* wr = W  + (size_t)r * OUTF;
  const float* mr = Wm + (size_t)r * OUTF;
  uint32_t word = 0;
#pragma unroll
  for (int i = 0; i < 8; ++i) {
    int col = w + 64 * i;
    uint32_t b = (wr[col] >= 0.0f ? 1u : 0u) + (mr[col] >= 0.0f ? 1u : 0u);
    word |= b << (4 * i);
  }
  tbl[tid] = word;
  tbl[(TBL2_B / 4) + tid] = 0x22222222u - word;   // fields 2-b (b<=2, no borrow)
  if (tid < 64) tbl[(DUMMY_B / 4) + tid] = 0x11111111u;
}

// ---------------------------------------------------------------------------
// main: one block per batch row, 8 waves; wave n handles bit-slice n.
//  - threshold search: seeded bounds (DPP) + up to 2 LDS-histogram rounds
//    (exact), residual bisection + stable tie fallback retained.
//  - positive-threshold fast path (midE > +0 key): selection is 1 cmp +
//    store per key, partial = 32 constant.  General path kept for exactness.
//  - gather uses readfirstlane'd wave-uniform row offsets -> SGPR-based
//    addressing.
// ---------------------------------------------------------------------------
__global__ __launch_bounds__(512, 4) void main_kernel(
    const float* __restrict__ latent,
    const uint32_t* __restrict__ tbl,
    float* __restrict__ out, int* __restrict__ partial)
{
  __shared__ __align__(16) uint32_t sel[NBITS][TOPK];   // BYTE offsets into tbl
  __shared__ float sums[NBITS][OUTF];
  __shared__ int   hist[NBITS][64];

  const int b    = blockIdx.x;
  const int wv   = threadIdx.x >> 6;        // bit index n
  const int lane = threadIdx.x & 63;

  // defensive prefill: every sel slot is a valid (zero-contribution) row
  if (lane < TOPK) sel[wv][lane] = (uint32_t)DUMMY_B;

  // ---- load 16 contiguous values, map to sortable keys, track lane max ----
  const float4* src =
      (const float4*)(latent + (size_t)b * INF + (size_t)wv * SLICE + lane * 16);
  uint32_t key[16];
  uint32_t lmax = 0u;
#pragma unroll
  for (int q = 0; q < 4; ++q) {
    float4 f = src[q];
    float vv[4] = {f.x, f.y, f.z, f.w};
#pragma unroll
    for (int t = 0; t < 4; ++t) {
      uint32_t k = fkey_u(__float_as_uint(vv[t]));
      key[4*q+t] = k;
      lmax = lmax > k ? lmax : k;
    }
  }
  // sign from key:  v>0 <=> key>0x80000000 ; v<0 <=> key<0x7FFFFFFF

  // ---- seeded bounds (valid for ANY input) --------------------------------
  uint32_t lo = wave_min_u32(lmax);
  uint32_t hi = wave_max_u32(lmax);

  // ---- threshold search: 2 histogram rounds + residual bisection ----------
  // Invariants: count(>=lo) >= 32 ; count(>=hi+1) < 32 ; base == count(>hi).
  uint32_t T = 0, midE = 0, cE = 0;
  int base  = 0;
  int state = 0;                            // 0 searching, 1 fast, 2 done(T)

#pragma unroll 1
  for (int round = 0; round < 2; ++round) {
    if (lo >= hi) break;
    uint32_t width = hi - lo;               // >= 1
    int bl  = 32 - __builtin_clz(width);
    int shr = bl > 6 ? bl - 6 : 0;          // (width-1)>>shr <= 63
    hist[wv][lane] = 0;
#pragma unroll
    for (int j = 0; j < 16; ++j) {
      uint32_t d1 = key[j] - lo - 1u;       // underflows for key<=lo
      if (d1 < width)                       // bin ONLY (lo, hi]
        atomicAdd(&hist[wv][d1 >> shr], 1);
    }
    int myc = hist[wv][lane];
    int P   = wave_prefix_incl(myc);
    int tot = __builtin_amdgcn_readlane(P, 63);
    // full count(key >= edge_lane), edge_lane = lo+1+(lane<<shr):
    int suf = base + (tot - P + myc);
    unsigned long long m32 = __ballot(suf == TOPK);
    if (m32) {                              // exact top-k at a bin edge
      int l = (int)__builtin_ctzll(m32);
      midE = lo + 1u + ((uint32_t)l << shr);
      uint32_t c = 0;
#pragma unroll
      for (int j = 0; j < 16; ++j) c += (key[j] >= midE) ? 1u : 0u;
      cE = c; state = 1; break;
    }
    unsigned long long mge = __ballot(suf > TOPK);
    if (mge == 0ULL) { T = lo; state = 2; break; }   // count(>=lo+1) < 32
    int bstar = 63 - (int)__builtin_clzll(mge);      // highest edge, suf>32
    uint32_t nlo = lo + 1u + ((uint32_t)bstar << shr);
    if (bstar < 63) {
      base = __builtin_amdgcn_readlane(suf, bstar + 1);  // count(> new hi)
      hi   = lo + ((uint32_t)(bstar + 1) << shr);
    }                                        // bstar==63: hi, base unchanged
    lo = nlo;
  }

  if (state == 0) {                          // residual exact bisection
    while (lo < hi) {
      uint32_t d   = hi - lo;
      uint32_t mid = lo + (d >> 1) + (d & 1u);
      uint32_t c = 0;
#pragma unroll
      for (int j = 0; j < 16; ++j) c += (key[j] >= mid) ? 1u : 0u;
      int cnt = __builtin_amdgcn_readlane(wave_prefix_incl((int)c), 63);
      if (cnt == TOPK) { midE = mid; cE = c; state = 1; break; }
      if (cnt > TOPK) lo = mid; else hi = mid - 1u;
    }
    if (state == 0) { T = lo; state = 2; }
  }

  const uint32_t pbase = ((uint32_t)(wv * SLICE + lane * 16)) << 8;  // row*256

  if (state == 1 && midE > 0x80000000u) {
    // ---- fast-fast path: tie-free AND all taken keys strictly positive ----
    int slot = wave_prefix_incl((int)cE) - (int)cE;   // exclusive prefix
#pragma unroll
    for (int j = 0; j < 16; ++j) {
      if (key[j] >= midE) sel[wv][slot++] = pbase + (j << 8);
    }
    if (lane == 0) partial[wv * BATCHN + b] = TOPK;   // all 32 nonzero
  } else if (state == 1) {
    // ---- fast path with sign folding (tie-free) ----------------------------
    int nzl = 0;
    int slot = wave_prefix_incl((int)cE) - (int)cE;
#pragma unroll
    for (int j = 0; j < 16; ++j) {
      uint32_t kk = key[j];
      if (kk >= midE) {
        bool ispos = kk > 0x80000000u;
        bool isneg = kk < 0x7FFFFFFFu;
        uint32_t off = ispos ? (pbase + (j << 8))
                     : (isneg ? (pbase + (j << 8) + TBL2_B) : (uint32_t)DUMMY_B);
        sel[wv][slot++] = off;
        nzl += (ispos || isneg) ? 1 : 0;
      }
    }
    int cnzP = wave_prefix_incl(nzl);
    if (lane == 63) partial[wv * BATCHN + b] = cnzP;
  } else {
    // ---- fallback: stable lowest-index-first tie handling (exact) ---------
    int nzl = 0;
    int cgt = 0, ceq = 0;
#pragma unroll
    for (int j = 0; j < 16; ++j) { cgt += (key[j] > T); ceq += (key[j] == T); }
    int packed  = (cgt << 16) | ceq;
    int sc_incl = wave_prefix_incl(packed);
    int tot2    = __builtin_amdgcn_readlane(sc_incl, 63);
    int total_g = tot2 >> 16;                // # strictly greater than T
    int nties   = TOPK - total_g;            // ties to take, lowest index first
    int excl    = sc_incl - packed;
    int posg    = excl >> 16;
    int pose    = excl & 0xFFFF;
#pragma unroll
    for (int j = 0; j < 16; ++j) {
      uint32_t kk  = key[j];
      bool isgt    = kk > T;
      bool iseq    = (kk == T);
      bool takeeq  = iseq && (pose < nties);
      bool take    = isgt || takeeq;
      bool ispos   = kk > 0x80000000u;
      bool isneg   = kk < 0x7FFFFFFFu;
      uint32_t off = ispos ? (pbase + (j << 8))
                   : (isneg ? (pbase + (j << 8) + TBL2_B) : (uint32_t)DUMMY_B);
      int slot = isgt ? posg : (total_g + pose);
      if (take) sel[wv][slot] = off;
      posg += isgt ? 1 : 0;
      pose += iseq ? 1 : 0;
      nzl  += (take && (ispos || isneg)) ? 1 : 0;
    }
    int cnzP = wave_prefix_incl(nzl);
    if (lane == 63) partial[wv * BATCHN + b] = cnzP;
  }

  // ---- gather: 32 loads, wave-uniform offsets -> SGPR addressing ----------
  uint32_t offr[TOPK];
  {
    const uint4* sp = (const uint4*)sel[wv];
#pragma unroll
    for (int q = 0; q < TOPK / 4; ++q) {
      uint4 e4 = sp[q];
      offr[4*q+0] = e4.x; offr[4*q+1] = e4.y;
      offr[4*q+2] = e4.z; offr[4*q+3] = e4.w;
    }
  }
  const uint32_t lb = (uint32_t)lane << 2;
  const char* tbase = (const char*)tbl;

#define LD(i)                                                                  \
  uint32_t w##i;                                                               \
  {                                                                            \
    uint32_t ro = (uint32_t)__builtin_amdgcn_readfirstlane((int)offr[i]);      \
    w##i = *(const uint32_t*)(tbase + (size_t)ro + lb);                        \
  }
  LD(0)  LD(1)  LD(2)  LD(3)  LD(4)  LD(5)  LD(6)  LD(7)
  LD(8)  LD(9)  LD(10) LD(11) LD(12) LD(13) LD(14) LD(15)
  LD(16) LD(17) LD(18) LD(19) LD(20) LD(21) LD(22) LD(23)
  LD(24) LD(25) LD(26) LD(27) LD(28) LD(29) LD(30) LD(31)
#undef LD
  asm volatile("" ::
    "v"(w0),"v"(w1),"v"(w2),"v"(w3),"v"(w4),"v"(w5),"v"(w6),"v"(w7),
    "v"(w8),"v"(w9),"v"(w10),"v"(w11),"v"(w12),"v"(w13),"v"(w14),"v"(w15));
  asm volatile("" ::
    "v"(w16),"v"(w17),"v"(w18),"v"(w19),"v"(w20),"v"(w21),"v"(w22),"v"(w23),
    "v"(w24),"v"(w25),"v"(w26),"v"(w27),"v"(w28),"v"(w29),"v"(w30),"v"(w31));

  // 5 independent <=7-deep chunks (4-bit fields: <=7*2=14 per nibble, safe)
  uint32_t g0 = (((w0 + w1) + (w2 + w3)) + ((w4 + w5) + w6));
  uint32_t g1 = (((w7 + w8) + (w9 + w10)) + ((w11 + w12) + w13));
  uint32_t g2 = (((w14 + w15) + (w16 + w17)) + ((w18 + w19) + w20));
  uint32_t g3 = (((w21 + w22) + (w23 + w24)) + ((w25 + w26) + w27));
  uint32_t g4 = ((w28 + w29) + (w30 + w31));
  const uint32_t M = 0x0F0F0F0Fu;
  uint32_t acc0 = (g0 & M) + (g1 & M) + (g2 & M) + (g3 & M) + (g4 & M);
  uint32_t acc1 = ((g0 >> 4) & M) + ((g1 >> 4) & M) + ((g2 >> 4) & M)
                + ((g3 >> 4) & M) + ((g4 >> 4) & M);

  // ---- per-column S = 2*F - 64, scaled ------------------------------------
  const float scale_n = 1.0f / (float)(1 << wv);   // 2^(6-n)*4/256 = 2^-n
#pragma unroll
  for (int i2 = 0; i2 < 4; ++i2) {
    int f0 = (int)((acc0 >> (8 * i2)) & 0xFFu);
    int f1 = (int)((acc1 >> (8 * i2)) & 0xFFu);
    sums[wv][lane + 128 * i2]      = scale_n * (float)(2 * f0 - 64);
    sums[wv][lane + 128 * i2 + 64] = scale_n * (float)(2 * f1 - 64);
  }

  __syncthreads();

  // ---- cumsum over bits, store result[n][b][col] --------------------------
  const int col = threadIdx.x;               // 0..511
  float racc = 0.0f;
  float* obase = out + 8 + (size_t)b * OUTF + col;
#pragma unroll
  for (int n2 = 0; n2 < NBITS; ++n2) {
    racc += sums[n2][col];
    obase[(size_t)n2 * BATCHN * OUTF] = racc;
  }
}

// ---------------------------------------------------------------------------
// finalize: latent_group[n] = (sum_b partial[n][b]) / BATCH
// ---------------------------------------------------------------------------
__global__ __launch_bounds__(512) void fin_kernel(
    const int* __restrict__ partial, float* __restrict__ out)
{
  const int wv   = threadIdx.x >> 6;
  const int lane = threadIdx.x & 63;
  const int* p = partial + wv * BATCHN;
  int s = 0;
#pragma unroll
  for (int k = 0; k < BATCHN / 64; ++k)
    s += p[lane + 64 * k];
#pragma unroll
  for (int d = 32; d >= 1; d >>= 1)
    s += __shfl_down(s, d);
  if (lane == 0) out[wv] = (float)s * (1.0f / (float)BATCHN);
}

extern "C" void kernel_launch(void* const* d_in, const int* in_sizes, int n_in,
                              void* d_out, int out_size, void* d_ws, size_t ws_size,
                              hipStream_t stream)
{
  const float* latent = (const float*)d_in[0];
  const float* W      = (const float*)d_in[1];
  const float* Wm     = (const float*)d_in[2];
  float* out = (float*)d_out;

  int*      partial = (int*)d_ws;                          // 128 KB
  uint32_t* tbl     = (uint32_t*)((char*)d_ws + 131072);   // ~4.2 MB tables

  prep_kernel<<<(INF * 64) / 256, 256, 0, stream>>>(W, Wm, tbl);
  main_kernel<<<BATCHN, 512, 0, stream>>>(latent, tbl, out, partial);
  fin_kernel<<<1, 512, 0, stream>>>(partial, out);
}